// Round 7
// baseline (336.133 us; speedup 1.0000x reference)
//
#include <hip/hip_runtime.h>
#include <hip/hip_bf16.h>

typedef __bf16 bf16_t;
typedef __bf16 bf16x8 __attribute__((ext_vector_type(8)));
typedef __bf16 bf16x4 __attribute__((ext_vector_type(4)));
typedef __bf16 bf16x2 __attribute__((ext_vector_type(2)));
typedef float f32x4 __attribute__((ext_vector_type(4)));
typedef float f32x2 __attribute__((ext_vector_type(2)));
typedef unsigned short u16;

#define NROWS 16384
#define KDIM  512
#define HID   256
#define ODIM  128
#define KS    8
#define LOG2E 1.44269504f

__device__ __forceinline__ f32x4 mfma16(bf16x8 a, bf16x8 b, f32x4 c) {
  return __builtin_amdgcn_mfma_f32_16x16x32_bf16(a, b, c, 0, 0, 0);
}

// async global->LDS DMA, 16B per lane; lds dst must be wave-uniform base (+lane*16)
__device__ __forceinline__ void dma16(const void* g, void* l) {
  __builtin_amdgcn_global_load_lds(
      (const __attribute__((address_space(1))) unsigned int*)g,
      (__attribute__((address_space(3))) unsigned int*)l, 16, 0, 0);
}

// ---------------------------------------------------------------------------
// prep: x fp32 -> xb bf16 ; W1 -> W1T bf16 ; W2 -> W2T bf16
// ---------------------------------------------------------------------------
__global__ __launch_bounds__(256) void prep(const float* __restrict__ x,
                                            const float* __restrict__ W1,
                                            const float* __restrict__ W2,
                                            bf16_t* __restrict__ xb,
                                            bf16_t* __restrict__ W1T,
                                            bf16_t* __restrict__ W2T) {
  int t = blockIdx.x * 256 + threadIdx.x;
  int stride = gridDim.x * 256;
  for (int e = t; e < NROWS * KDIM / 4; e += stride) {
    f32x4 v = *(const f32x4*)(x + (size_t)e * 4);
    bf16x4 pk;
    pk[0] = (bf16_t)v[0]; pk[1] = (bf16_t)v[1];
    pk[2] = (bf16_t)v[2]; pk[3] = (bf16_t)v[3];
    *(bf16x4*)(xb + (size_t)e * 4) = pk;
  }
  for (int e = t; e < HID * KDIM; e += stride) {
    int n = e >> 9, k = e & 511;
    W1T[e] = (bf16_t)W1[k * HID + n];
  }
  for (int e = t; e < ODIM * HID; e += stride) {
    int n = e >> 8, k = e & 255;
    W2T[e] = (bf16_t)W2[k * ODIM + n];
  }
}

// ---------------------------------------------------------------------------
// gemm1: h1 = LeakyReLU(xb @ W1 + b1), bf16 out [16384][256]
// ---------------------------------------------------------------------------
__global__ __launch_bounds__(256) void gemm1(const bf16_t* __restrict__ xb,
                                             const bf16_t* __restrict__ W1T,
                                             const float* __restrict__ b1,
                                             bf16_t* __restrict__ h1) {
  __shared__ u16 As[128 * 40];
  __shared__ u16 Bs[64 * 40];
  int tid = threadIdx.x;
  int lane = tid & 63, w = tid >> 6;
  int r = lane & 15, q = lane >> 4;
  int wm = w & 1, wn = w >> 1;
  int mbase = blockIdx.x * 128, nbase = blockIdx.y * 64;

  f32x4 acc[4][2];
#pragma unroll
  for (int ms = 0; ms < 4; ms++)
#pragma unroll
    for (int ns = 0; ns < 2; ns++) acc[ms][ns] = (f32x4){0.f, 0.f, 0.f, 0.f};

  for (int kb = 0; kb < KDIM; kb += 32) {
#pragma unroll
    for (int i = 0; i < 2; i++) {
      int g = tid + 256 * i;
      int rr = g >> 2, c = (g & 3) * 8;
      *(bf16x8*)&As[rr * 40 + c] =
          *(const bf16x8*)(xb + (size_t)(mbase + rr) * KDIM + kb + c);
    }
    {
      int rr = tid >> 2, c = (tid & 3) * 8;
      *(bf16x8*)&Bs[rr * 40 + c] =
          *(const bf16x8*)(W1T + (size_t)(nbase + rr) * KDIM + kb + c);
    }
    __syncthreads();
    bf16x8 af[4], bfr[2];
#pragma unroll
    for (int ms = 0; ms < 4; ms++)
      af[ms] = *(bf16x8*)&As[(wm * 64 + ms * 16 + r) * 40 + q * 8];
#pragma unroll
    for (int ns = 0; ns < 2; ns++)
      bfr[ns] = *(bf16x8*)&Bs[(wn * 32 + ns * 16 + r) * 40 + q * 8];
#pragma unroll
    for (int ms = 0; ms < 4; ms++)
#pragma unroll
      for (int ns = 0; ns < 2; ns++)
        acc[ms][ns] = mfma16(af[ms], bfr[ns], acc[ms][ns]);
    __syncthreads();
  }
#pragma unroll
  for (int ns = 0; ns < 2; ns++) {
    int col = nbase + wn * 32 + ns * 16 + r;
    float bias = b1[col];
#pragma unroll
    for (int ms = 0; ms < 4; ms++) {
      int row0 = mbase + wm * 64 + ms * 16 + q * 4;
#pragma unroll
      for (int reg = 0; reg < 4; reg++) {
        float v = acc[ms][ns][reg] + bias;
        v = v >= 0.f ? v : 0.01f * v;
        h1[(size_t)(row0 + reg) * HID + col] = (bf16_t)v;
      }
    }
  }
}

// ---------------------------------------------------------------------------
// gemm2: h = h1 @ W2 + b2 -> hb bf16 [16384][128], hT bf16 [128][16384]
// ---------------------------------------------------------------------------
__global__ __launch_bounds__(256) void gemm2(const bf16_t* __restrict__ h1,
                                             const bf16_t* __restrict__ W2T,
                                             const float* __restrict__ b2,
                                             bf16_t* __restrict__ hb,
                                             bf16_t* __restrict__ hT) {
  __shared__ u16 As[128 * 40];
  __shared__ u16 Bs[64 * 40];
  int tid = threadIdx.x;
  int lane = tid & 63, w = tid >> 6;
  int r = lane & 15, q = lane >> 4;
  int wm = w & 1, wn = w >> 1;
  int mbase = blockIdx.x * 128, nbase = blockIdx.y * 64;

  f32x4 acc[4][2];
#pragma unroll
  for (int ms = 0; ms < 4; ms++)
#pragma unroll
    for (int ns = 0; ns < 2; ns++) acc[ms][ns] = (f32x4){0.f, 0.f, 0.f, 0.f};

  for (int kb = 0; kb < HID; kb += 32) {
#pragma unroll
    for (int i = 0; i < 2; i++) {
      int g = tid + 256 * i;
      int rr = g >> 2, c = (g & 3) * 8;
      *(bf16x8*)&As[rr * 40 + c] =
          *(const bf16x8*)(h1 + (size_t)(mbase + rr) * HID + kb + c);
    }
    {
      int rr = tid >> 2, c = (tid & 3) * 8;
      *(bf16x8*)&Bs[rr * 40 + c] =
          *(const bf16x8*)(W2T + (size_t)(nbase + rr) * HID + kb + c);
    }
    __syncthreads();
    bf16x8 af[4], bfr[2];
#pragma unroll
    for (int ms = 0; ms < 4; ms++)
      af[ms] = *(bf16x8*)&As[(wm * 64 + ms * 16 + r) * 40 + q * 8];
#pragma unroll
    for (int ns = 0; ns < 2; ns++)
      bfr[ns] = *(bf16x8*)&Bs[(wn * 32 + ns * 16 + r) * 40 + q * 8];
#pragma unroll
    for (int ms = 0; ms < 4; ms++)
#pragma unroll
      for (int ns = 0; ns < 2; ns++)
        acc[ms][ns] = mfma16(af[ms], bfr[ns], acc[ms][ns]);
    __syncthreads();
  }
#pragma unroll
  for (int ns = 0; ns < 2; ns++) {
    int col = nbase + wn * 32 + ns * 16 + r;
    float bias = b2[col];
#pragma unroll
    for (int ms = 0; ms < 4; ms++) {
      int row0 = mbase + wm * 64 + ms * 16 + q * 4;
      bf16x4 pk;
#pragma unroll
      for (int reg = 0; reg < 4; reg++) {
        float v = acc[ms][ns][reg] + bias;
        hb[(size_t)(row0 + reg) * ODIM + col] = (bf16_t)v;
        pk[reg] = (bf16_t)v;
      }
      *(bf16x4*)(hT + (size_t)col * NROWS + row0) = pk;
    }
  }
}

// ---------------------------------------------------------------------------
// flash (split-K, DMA-pipelined): grid = 128 qtiles x KS, 512-thread blocks.
// 8 waves x 16 q-rows each; waves 0-3 stage (0,1 -> KA; 2,3 -> KT dbuf),
// all 8 compute. XCD-aware decode (ksplit = bid & 7). This round:
// (a) Pm row stride 40 -> 36 shorts (72B): 18r mod 32 hits all 16 even
//     residues once, so b64 writes / b128 reads spread 4-per-residue
//     (= hardware minimum) instead of the period-8 collapse at 80B that
//     caused the 6.29M bank-conflict cycles.
// (b) softmax denominator via ones-row MFMA (D = 1*P gives column sums on
//     the matrix pipe) instead of an 8-add + 2-shfl serial reduce; l now
//     sums the same bf16-quantized P that O sums.
// Barrier/DMA pattern unchanged from the verified round-5/6 build.
// ---------------------------------------------------------------------------
__global__ __launch_bounds__(512, 6) void flash(const bf16_t* __restrict__ hb,
                                                const bf16_t* __restrict__ hT,
                                                bf16_t* __restrict__ OpA,
                                                bf16_t* __restrict__ OpB,
                                                float* __restrict__ Ml) {
  __shared__ __align__(16) u16 KA[8 * 512];       // 8 frag blocks of 1KB
  __shared__ __align__(16) u16 KT[2][8 * 512];    // double-buffered
  __shared__ __align__(16) u16 Pm[8 * 16 * 36];   // per-wave P [16 qr][36]

  int tid = threadIdx.x;
  int lane = tid & 63, w = tid >> 6;   // w in 0..7
  int r = lane & 15, q = lane >> 4;
  int ksplit = blockIdx.x & 7;         // XCD-aware: one ksplit per XCD
  int qtile = blockIdx.x >> 3;
  int qbase = qtile * 128 + w * 16;    // 16 q-rows per wave
  int kbase = ksplit * (NROWS / KS);
  const int niter = (NROWS / KS) / 32;  // 64

  // staging: waves 0,1 -> KA blocks (mt=w, kk=j); waves 2,3 -> KT blocks
  // m8=(w-2)*4+j; waves 4-7 issue no DMAs.
  const char* gbase = nullptr;
  size_t jmul = 0;
  int ginc = 0;
  u16* dbase = nullptr;
  if (w < 2) {
    gbase = (const char*)(hb + (size_t)(kbase + w * 16 + r) * ODIM + q * 8);
    jmul = 32 * 2;            // kk stride: 32 shorts
    ginc = 32 * ODIM * 2;     // next 32-k chunk
    dbase = KA + w * 4 * 512;
  } else if (w < 4) {
    gbase = (const char*)(hT + (size_t)((w - 2) * 64 + r) * NROWS + kbase + q * 8);
    jmul = (size_t)16 * NROWS * 2;  // m8 stride: 16 rows
    ginc = 32 * 2;                  // next 32-k chunk
    dbase = KT[0] + (w - 2) * 4 * 512;
  }

  // Q fragments resident in registers (16 rows per wave)
  bf16x8 qf[4];
  {
    int qrow = qbase + r;
#pragma unroll
    for (int kk = 0; kk < 4; kk++)
      qf[kk] = *(const bf16x8*)(hb + (size_t)qrow * ODIM + kk * 32 + q * 8);
  }

  // ones A-fragment for the denominator MFMA
  bf16x8 ones8;
#pragma unroll
  for (int j = 0; j < 8; j++) ones8[j] = (bf16_t)1.0f;

  f32x4 oa[8];
#pragma unroll
  for (int m8 = 0; m8 < 8; m8++) oa[m8] = (f32x4){0.f, 0.f, 0.f, 0.f};
  f32x4 oal = (f32x4){0.f, 0.f, 0.f, 0.f};  // l accumulator (col sums of P)
  float m_run = 0.f;
  float nmlog = 0.f;  // -m_run * log2(e), kept in sync

  // issue iter-0 DMAs (KT -> buffer 0)
  if (w < 4) {
#pragma unroll
    for (int j = 0; j < 4; j++) dma16(gbase + j * jmul, dbase + j * 512);
    gbase += ginc;
  }

  for (int it = 0; it < niter; it++) {
    __syncthreads();  // drains vmcnt -> KA(it), KT(it) ready

    // ---- S^T = K_chunk . Q^T ----
    f32x4 s[2];
    s[0] = (f32x4){0.f, 0.f, 0.f, 0.f};
    s[1] = (f32x4){0.f, 0.f, 0.f, 0.f};
#pragma unroll
    for (int mt = 0; mt < 2; mt++)
#pragma unroll
      for (int kk = 0; kk < 4; kk++) {
        bf16x8 af = *(bf16x8*)&KA[(mt * 4 + kk) * 512 + lane * 8];
        s[mt] = mfma16(af, qf[kk], s[mt]);
      }
    __syncthreads();  // all waves done reading KA

    // ---- prefetch next chunk (KA single-buf now free; KT -> other buffer) ----
    if (it + 1 < niter && w < 4) {
      u16* d = dbase;
      if (w >= 2) d += ((it + 1) & 1) * 4096;
#pragma unroll
      for (int j = 0; j < 4; j++) dma16(gbase + j * jmul, d + j * 512);
      gbase += ginc;
    }

    // ---- masked online softmax (defer-max THR=8, exp2 domain) ----
    // m_run >= 0 >= masked-out scores, so unconditional fmax is exact.
    float mx;
    {
      float m = m_run;
#pragma unroll
      for (int mt = 0; mt < 2; mt++)
#pragma unroll
        for (int reg = 0; reg < 4; reg++) m = fmaxf(m, s[mt][reg]);
      m = fmaxf(m, __shfl_xor(m, 16, 64));
      m = fmaxf(m, __shfl_xor(m, 32, 64));
      mx = m;
    }
    if (__any(mx > m_run + 8.f)) {
      float sc = __builtin_amdgcn_exp2f((m_run - mx) * LOG2E);
      m_run = mx;
      nmlog = -mx * LOG2E;
#pragma unroll
      for (int m8 = 0; m8 < 8; m8++)
#pragma unroll
        for (int reg = 0; reg < 4; reg++) oa[m8][reg] *= sc;
#pragma unroll
      for (int reg = 0; reg < 4; reg++) oal[reg] *= sc;
    }
    {
      bf16x4 pk[2];
#pragma unroll
      for (int mt = 0; mt < 2; mt++)
#pragma unroll
        for (int reg = 0; reg < 4; reg++) {
          float v = s[mt][reg];
          float p = __builtin_amdgcn_exp2f(fmaf(v, LOG2E, nmlog));
          p = v > 0.f ? p : 0.f;
          pk[mt][reg] = (bf16_t)p;
        }
#pragma unroll
      for (int mt = 0; mt < 2; mt++)
        *(bf16x4*)&Pm[w * 576 + r * 36 + mt * 16 + q * 4] = pk[mt];
    }

    // ---- O^T += K^T . P^T ; l += 1 . P^T ----
    bf16x8 pf = *(bf16x8*)&Pm[w * 576 + r * 36 + q * 8];
    const u16* kt = KT[it & 1];
#pragma unroll
    for (int m8 = 0; m8 < 8; m8++) {
      bf16x8 af = *(bf16x8*)&kt[m8 * 512 + lane * 8];
      oa[m8] = mfma16(af, pf, oa[m8]);
    }
    oal = mfma16(ones8, pf, oal);
  }

  // ---- write partials ----
  bf16_t* op = ksplit < 6 ? OpA + (size_t)ksplit * NROWS * ODIM
                          : OpB + (size_t)(ksplit - 6) * NROWS * ODIM;
  {
    int row = qbase + r;
#pragma unroll
    for (int m8 = 0; m8 < 8; m8++) {
      bf16x4 pk;
#pragma unroll
      for (int reg = 0; reg < 4; reg++) pk[reg] = (bf16_t)oa[m8][reg];
      *(bf16x4*)(op + (size_t)row * ODIM + m8 * 16 + q * 4) = pk;
    }
    if (q == 0) {
      Ml[(ksplit * NROWS + row) * 2 + 0] = m_run;
      Ml[(ksplit * NROWS + row) * 2 + 1] = oal[0];
    }
  }
}

// ---------------------------------------------------------------------------
// merge: combine KS partials, apply alpha/beta/h, log_softmax, write out.
// ---------------------------------------------------------------------------
__global__ __launch_bounds__(256) void merge_ls(const bf16_t* __restrict__ OpA,
                                                const bf16_t* __restrict__ OpB,
                                                const float* __restrict__ Ml,
                                                const bf16_t* __restrict__ hbf,
                                                const float* __restrict__ alpha_p,
                                                const float* __restrict__ beta_p,
                                                float* __restrict__ out) {
  int tid = threadIdx.x, lane = tid & 63, w = tid >> 6;
  float al = alpha_p[0], be = beta_p[0];
  for (int i = 0; i < 8; i++) {
    int row = blockIdx.x * 32 + w * 8 + i;
    float mk[KS], lk[KS], ak[KS];
    float M = 0.f;
#pragma unroll
    for (int ksp = 0; ksp < KS; ksp++) {
      mk[ksp] = Ml[(ksp * NROWS + row) * 2 + 0];
      lk[ksp] = Ml[(ksp * NROWS + row) * 2 + 1];
      M = fmaxf(M, mk[ksp]);
    }
    float lt = 0.f;
#pragma unroll
    for (int ksp = 0; ksp < KS; ksp++) {
      ak[ksp] = __expf(mk[ksp] - M);
      lt += lk[ksp] * ak[ksp];
    }
    float inv = al / lt;
    int d0 = lane * 2;
    float a0 = 0.f, a1 = 0.f;
#pragma unroll
    for (int ksp = 0; ksp < KS; ksp++) {
      const bf16_t* op = ksp < 6 ? OpA + (size_t)ksp * NROWS * ODIM
                                 : OpB + (size_t)(ksp - 6) * NROWS * ODIM;
      bf16x2 v = *(const bf16x2*)(op + (size_t)row * ODIM + d0);
      a0 += ak[ksp] * (float)v[0];
      a1 += ak[ksp] * (float)v[1];
    }
    bf16x2 hv = *(const bf16x2*)(hbf + (size_t)row * ODIM + d0);
    float v0 = inv * a0 + be * (float)hv[0];
    float v1 = inv * a1 + be * (float)hv[1];
    float mxv = fmaxf(v0, v1);
#pragma unroll
    for (int off = 1; off < 64; off <<= 1) mxv = fmaxf(mxv, __shfl_xor(mxv, off, 64));
    float se = __expf(v0 - mxv) + __expf(v1 - mxv);
#pragma unroll
    for (int off = 1; off < 64; off <<= 1) se += __shfl_xor(se, off, 64);
    float lz = mxv + __logf(se);
    f32x2 st = {v0 - lz, v1 - lz};
    *(f32x2*)(out + (size_t)row * ODIM + d0) = st;
  }
}

// ---------------------------------------------------------------------------
extern "C" void kernel_launch(void* const* d_in, const int* in_sizes, int n_in,
                              void* d_out, int out_size, void* d_ws,
                              size_t ws_size, hipStream_t stream) {
  const float* x     = (const float*)d_in[0];
  const float* W1    = (const float*)d_in[2];
  const float* b1    = (const float*)d_in[3];
  const float* W2    = (const float*)d_in[4];
  const float* b2    = (const float*)d_in[5];
  const float* alpha = (const float*)d_in[6];
  const float* beta  = (const float*)d_in[7];

  char* ws = (char*)d_ws;
  // [0, 25493504): xb(16M) + W1T(256K) + W2T(64K) + h1(8M) — all dead during
  // flash/merge, reused as Op splits 0..5 (24MB).
  bf16_t* xb  = (bf16_t*)(ws + 0);
  bf16_t* W1T = (bf16_t*)(ws + 16777216);
  bf16_t* W2T = (bf16_t*)(ws + 17039360);
  bf16_t* h1  = (bf16_t*)(ws + 17104896);   // ends 25493504
  bf16_t* hbf = (bf16_t*)(ws + 25493504);   // 4MB
  bf16_t* hT  = (bf16_t*)(ws + 29687808);   // 4MB
  float*  Ml  = (float*)(ws + 33882112);    // 1MB
  bf16_t* OpB = (bf16_t*)(ws + 34930688);   // 2 x 4MB -> total 43.3MB
  bf16_t* OpA = (bf16_t*)(ws + 0);          // overlays xb/W1T/W2T/h1
  float* outp = (float*)d_out;

  prep<<<1024, 256, 0, stream>>>(x, W1, W2, xb, W1T, W2T);
  gemm1<<<dim3(128, 4), 256, 0, stream>>>(xb, W1T, b1, h1);
  gemm2<<<dim3(128, 2), 256, 0, stream>>>(h1, W2T, b2, hbf, hT);
  flash<<<128 * KS, 512, 0, stream>>>(hbf, hT, OpA, OpB, Ml);
  merge_ls<<<512, 256, 0, stream>>>(OpA, OpB, Ml, hbf, alpha, beta, outp);
}

// Round 8
// 297.157 us; speedup vs baseline: 1.1312x; 1.1312x over previous
//
#include <hip/hip_runtime.h>
#include <hip/hip_bf16.h>

typedef __bf16 bf16_t;
typedef __bf16 bf16x8 __attribute__((ext_vector_type(8)));
typedef __bf16 bf16x4 __attribute__((ext_vector_type(4)));
typedef __bf16 bf16x2 __attribute__((ext_vector_type(2)));
typedef float f32x4 __attribute__((ext_vector_type(4)));
typedef float f32x2 __attribute__((ext_vector_type(2)));
typedef unsigned short u16;

#define NROWS 16384
#define KDIM  512
#define HID   256
#define ODIM  128
#define KS    8
#define LOG2E 1.44269504f

__device__ __forceinline__ f32x4 mfma16(bf16x8 a, bf16x8 b, f32x4 c) {
  return __builtin_amdgcn_mfma_f32_16x16x32_bf16(a, b, c, 0, 0, 0);
}

// async global->LDS DMA, 16B per lane; lds dst must be wave-uniform base (+lane*16)
__device__ __forceinline__ void dma16(const void* g, void* l) {
  __builtin_amdgcn_global_load_lds(
      (const __attribute__((address_space(1))) unsigned int*)g,
      (__attribute__((address_space(3))) unsigned int*)l, 16, 0, 0);
}

// ---------------------------------------------------------------------------
// prep: x fp32 -> xb bf16 ; W1 -> W1T bf16 ; W2 -> W2T bf16
// ---------------------------------------------------------------------------
__global__ __launch_bounds__(256) void prep(const float* __restrict__ x,
                                            const float* __restrict__ W1,
                                            const float* __restrict__ W2,
                                            bf16_t* __restrict__ xb,
                                            bf16_t* __restrict__ W1T,
                                            bf16_t* __restrict__ W2T) {
  int t = blockIdx.x * 256 + threadIdx.x;
  int stride = gridDim.x * 256;
  for (int e = t; e < NROWS * KDIM / 4; e += stride) {
    f32x4 v = *(const f32x4*)(x + (size_t)e * 4);
    bf16x4 pk;
    pk[0] = (bf16_t)v[0]; pk[1] = (bf16_t)v[1];
    pk[2] = (bf16_t)v[2]; pk[3] = (bf16_t)v[3];
    *(bf16x4*)(xb + (size_t)e * 4) = pk;
  }
  for (int e = t; e < HID * KDIM; e += stride) {
    int n = e >> 9, k = e & 511;
    W1T[e] = (bf16_t)W1[k * HID + n];
  }
  for (int e = t; e < ODIM * HID; e += stride) {
    int n = e >> 8, k = e & 255;
    W2T[e] = (bf16_t)W2[k * ODIM + n];
  }
}

// ---------------------------------------------------------------------------
// gemm1: h1 = LeakyReLU(xb @ W1 + b1), bf16 out [16384][256]
// ---------------------------------------------------------------------------
__global__ __launch_bounds__(256) void gemm1(const bf16_t* __restrict__ xb,
                                             const bf16_t* __restrict__ W1T,
                                             const float* __restrict__ b1,
                                             bf16_t* __restrict__ h1) {
  __shared__ u16 As[128 * 40];
  __shared__ u16 Bs[64 * 40];
  int tid = threadIdx.x;
  int lane = tid & 63, w = tid >> 6;
  int r = lane & 15, q = lane >> 4;
  int wm = w & 1, wn = w >> 1;
  int mbase = blockIdx.x * 128, nbase = blockIdx.y * 64;

  f32x4 acc[4][2];
#pragma unroll
  for (int ms = 0; ms < 4; ms++)
#pragma unroll
    for (int ns = 0; ns < 2; ns++) acc[ms][ns] = (f32x4){0.f, 0.f, 0.f, 0.f};

  for (int kb = 0; kb < KDIM; kb += 32) {
#pragma unroll
    for (int i = 0; i < 2; i++) {
      int g = tid + 256 * i;
      int rr = g >> 2, c = (g & 3) * 8;
      *(bf16x8*)&As[rr * 40 + c] =
          *(const bf16x8*)(xb + (size_t)(mbase + rr) * KDIM + kb + c);
    }
    {
      int rr = tid >> 2, c = (tid & 3) * 8;
      *(bf16x8*)&Bs[rr * 40 + c] =
          *(const bf16x8*)(W1T + (size_t)(nbase + rr) * KDIM + kb + c);
    }
    __syncthreads();
    bf16x8 af[4], bfr[2];
#pragma unroll
    for (int ms = 0; ms < 4; ms++)
      af[ms] = *(bf16x8*)&As[(wm * 64 + ms * 16 + r) * 40 + q * 8];
#pragma unroll
    for (int ns = 0; ns < 2; ns++)
      bfr[ns] = *(bf16x8*)&Bs[(wn * 32 + ns * 16 + r) * 40 + q * 8];
#pragma unroll
    for (int ms = 0; ms < 4; ms++)
#pragma unroll
      for (int ns = 0; ns < 2; ns++)
        acc[ms][ns] = mfma16(af[ms], bfr[ns], acc[ms][ns]);
    __syncthreads();
  }
#pragma unroll
  for (int ns = 0; ns < 2; ns++) {
    int col = nbase + wn * 32 + ns * 16 + r;
    float bias = b1[col];
#pragma unroll
    for (int ms = 0; ms < 4; ms++) {
      int row0 = mbase + wm * 64 + ms * 16 + q * 4;
#pragma unroll
      for (int reg = 0; reg < 4; reg++) {
        float v = acc[ms][ns][reg] + bias;
        v = v >= 0.f ? v : 0.01f * v;
        h1[(size_t)(row0 + reg) * HID + col] = (bf16_t)v;
      }
    }
  }
}

// ---------------------------------------------------------------------------
// gemm2: h = h1 @ W2 + b2 -> hb bf16 [16384][128], hT bf16 [128][16384]
// ---------------------------------------------------------------------------
__global__ __launch_bounds__(256) void gemm2(const bf16_t* __restrict__ h1,
                                             const bf16_t* __restrict__ W2T,
                                             const float* __restrict__ b2,
                                             bf16_t* __restrict__ hb,
                                             bf16_t* __restrict__ hT) {
  __shared__ u16 As[128 * 40];
  __shared__ u16 Bs[64 * 40];
  int tid = threadIdx.x;
  int lane = tid & 63, w = tid >> 6;
  int r = lane & 15, q = lane >> 4;
  int wm = w & 1, wn = w >> 1;
  int mbase = blockIdx.x * 128, nbase = blockIdx.y * 64;

  f32x4 acc[4][2];
#pragma unroll
  for (int ms = 0; ms < 4; ms++)
#pragma unroll
    for (int ns = 0; ns < 2; ns++) acc[ms][ns] = (f32x4){0.f, 0.f, 0.f, 0.f};

  for (int kb = 0; kb < HID; kb += 32) {
#pragma unroll
    for (int i = 0; i < 2; i++) {
      int g = tid + 256 * i;
      int rr = g >> 2, c = (g & 3) * 8;
      *(bf16x8*)&As[rr * 40 + c] =
          *(const bf16x8*)(h1 + (size_t)(mbase + rr) * HID + kb + c);
    }
    {
      int rr = tid >> 2, c = (tid & 3) * 8;
      *(bf16x8*)&Bs[rr * 40 + c] =
          *(const bf16x8*)(W2T + (size_t)(nbase + rr) * HID + kb + c);
    }
    __syncthreads();
    bf16x8 af[4], bfr[2];
#pragma unroll
    for (int ms = 0; ms < 4; ms++)
      af[ms] = *(bf16x8*)&As[(wm * 64 + ms * 16 + r) * 40 + q * 8];
#pragma unroll
    for (int ns = 0; ns < 2; ns++)
      bfr[ns] = *(bf16x8*)&Bs[(wn * 32 + ns * 16 + r) * 40 + q * 8];
#pragma unroll
    for (int ms = 0; ms < 4; ms++)
#pragma unroll
      for (int ns = 0; ns < 2; ns++)
        acc[ms][ns] = mfma16(af[ms], bfr[ns], acc[ms][ns]);
    __syncthreads();
  }
#pragma unroll
  for (int ns = 0; ns < 2; ns++) {
    int col = nbase + wn * 32 + ns * 16 + r;
    float bias = b2[col];
#pragma unroll
    for (int ms = 0; ms < 4; ms++) {
      int row0 = mbase + wm * 64 + ms * 16 + q * 4;
      bf16x4 pk;
#pragma unroll
      for (int reg = 0; reg < 4; reg++) {
        float v = acc[ms][ns][reg] + bias;
        hb[(size_t)(row0 + reg) * ODIM + col] = (bf16_t)v;
        pk[reg] = (bf16_t)v;
      }
      *(bf16x4*)(hT + (size_t)col * NROWS + row0) = pk;
    }
  }
}

// ---------------------------------------------------------------------------
// flash (split-K, DMA-pipelined): grid = 128 qtiles x KS, 512-thread blocks.
// 8 waves x 16 q-rows each; waves 0-3 stage (0,1 -> KA; 2,3 -> KT dbuf),
// all 8 compute. XCD-aware decode (ksplit = bid & 7). Softmax: defer-max
// THR=8, exp2-domain fused fma, unconditional fmax scan. EXACT round-6
// verified source (198 us; Pm stride 40, shfl l-reduce). Round-7's
// stride-36 + ones-MFMA were reverted: conflicts are hidden by 8-wave
// overlap (not critical-path) and the pair cost +35 us of stall.
// ---------------------------------------------------------------------------
__global__ __launch_bounds__(512, 6) void flash(const bf16_t* __restrict__ hb,
                                                const bf16_t* __restrict__ hT,
                                                bf16_t* __restrict__ OpA,
                                                bf16_t* __restrict__ OpB,
                                                float* __restrict__ Ml) {
  __shared__ __align__(16) u16 KA[8 * 512];       // 8 frag blocks of 1KB
  __shared__ __align__(16) u16 KT[2][8 * 512];    // double-buffered
  __shared__ __align__(16) u16 Pm[8 * 16 * 40];   // per-wave P [16 qr][kr]

  int tid = threadIdx.x;
  int lane = tid & 63, w = tid >> 6;   // w in 0..7
  int r = lane & 15, q = lane >> 4;
  int ksplit = blockIdx.x & 7;         // XCD-aware: one ksplit per XCD
  int qtile = blockIdx.x >> 3;
  int qbase = qtile * 128 + w * 16;    // 16 q-rows per wave
  int kbase = ksplit * (NROWS / KS);
  const int niter = (NROWS / KS) / 32;  // 64

  // staging: waves 0,1 -> KA blocks (mt=w, kk=j); waves 2,3 -> KT blocks
  // m8=(w-2)*4+j; waves 4-7 issue no DMAs.
  const char* gbase = nullptr;
  size_t jmul = 0;
  int ginc = 0;
  u16* dbase = nullptr;
  if (w < 2) {
    gbase = (const char*)(hb + (size_t)(kbase + w * 16 + r) * ODIM + q * 8);
    jmul = 32 * 2;            // kk stride: 32 shorts
    ginc = 32 * ODIM * 2;     // next 32-k chunk
    dbase = KA + w * 4 * 512;
  } else if (w < 4) {
    gbase = (const char*)(hT + (size_t)((w - 2) * 64 + r) * NROWS + kbase + q * 8);
    jmul = (size_t)16 * NROWS * 2;  // m8 stride: 16 rows
    ginc = 32 * 2;                  // next 32-k chunk
    dbase = KT[0] + (w - 2) * 4 * 512;
  }

  // Q fragments resident in registers (16 rows per wave)
  bf16x8 qf[4];
  {
    int qrow = qbase + r;
#pragma unroll
    for (int kk = 0; kk < 4; kk++)
      qf[kk] = *(const bf16x8*)(hb + (size_t)qrow * ODIM + kk * 32 + q * 8);
  }

  f32x4 oa[8];
#pragma unroll
  for (int m8 = 0; m8 < 8; m8++) oa[m8] = (f32x4){0.f, 0.f, 0.f, 0.f};
  float m_run = 0.f, l_run = 0.f;
  float nmlog = 0.f;  // -m_run * log2(e), kept in sync

  // issue iter-0 DMAs (KT -> buffer 0)
  if (w < 4) {
#pragma unroll
    for (int j = 0; j < 4; j++) dma16(gbase + j * jmul, dbase + j * 512);
    gbase += ginc;
  }

  for (int it = 0; it < niter; it++) {
    __syncthreads();  // drains vmcnt -> KA(it), KT(it) ready

    // ---- S^T = K_chunk . Q^T ----
    f32x4 s[2];
    s[0] = (f32x4){0.f, 0.f, 0.f, 0.f};
    s[1] = (f32x4){0.f, 0.f, 0.f, 0.f};
#pragma unroll
    for (int mt = 0; mt < 2; mt++)
#pragma unroll
      for (int kk = 0; kk < 4; kk++) {
        bf16x8 af = *(bf16x8*)&KA[(mt * 4 + kk) * 512 + lane * 8];
        s[mt] = mfma16(af, qf[kk], s[mt]);
      }
    __syncthreads();  // all waves done reading KA

    // ---- prefetch next chunk (KA single-buf now free; KT -> other buffer) ----
    if (it + 1 < niter && w < 4) {
      u16* d = dbase;
      if (w >= 2) d += ((it + 1) & 1) * 4096;
#pragma unroll
      for (int j = 0; j < 4; j++) dma16(gbase + j * jmul, d + j * 512);
      gbase += ginc;
    }

    // ---- masked online softmax (defer-max THR=8, exp2 domain) ----
    // m_run >= 0 >= masked-out scores, so unconditional fmax is exact.
    float mx;
    {
      float m = m_run;
#pragma unroll
      for (int mt = 0; mt < 2; mt++)
#pragma unroll
        for (int reg = 0; reg < 4; reg++) m = fmaxf(m, s[mt][reg]);
      m = fmaxf(m, __shfl_xor(m, 16, 64));
      m = fmaxf(m, __shfl_xor(m, 32, 64));
      mx = m;
    }
    if (__any(mx > m_run + 8.f)) {
      float sc = __builtin_amdgcn_exp2f((m_run - mx) * LOG2E);
      m_run = mx;
      nmlog = -mx * LOG2E;
      l_run *= sc;
#pragma unroll
      for (int m8 = 0; m8 < 8; m8++)
#pragma unroll
        for (int reg = 0; reg < 4; reg++) oa[m8][reg] *= sc;
    }
    {
      float rs = 0.f;
      bf16x4 pk[2];
#pragma unroll
      for (int mt = 0; mt < 2; mt++)
#pragma unroll
        for (int reg = 0; reg < 4; reg++) {
          float v = s[mt][reg];
          float p = __builtin_amdgcn_exp2f(fmaf(v, LOG2E, nmlog));
          p = v > 0.f ? p : 0.f;
          rs += p;
          pk[mt][reg] = (bf16_t)p;
        }
      rs += __shfl_xor(rs, 16, 64);
      rs += __shfl_xor(rs, 32, 64);
      l_run += rs;
#pragma unroll
      for (int mt = 0; mt < 2; mt++)
        *(bf16x4*)&Pm[w * 640 + r * 40 + mt * 16 + q * 4] = pk[mt];
    }

    // ---- O^T += K^T . P^T ----
    bf16x8 pf = *(bf16x8*)&Pm[w * 640 + r * 40 + q * 8];
    const u16* kt = KT[it & 1];
#pragma unroll
    for (int m8 = 0; m8 < 8; m8++) {
      bf16x8 af = *(bf16x8*)&kt[m8 * 512 + lane * 8];
      oa[m8] = mfma16(af, pf, oa[m8]);
    }
  }

  // ---- write partials ----
  bf16_t* op = ksplit < 6 ? OpA + (size_t)ksplit * NROWS * ODIM
                          : OpB + (size_t)(ksplit - 6) * NROWS * ODIM;
  {
    int row = qbase + r;
#pragma unroll
    for (int m8 = 0; m8 < 8; m8++) {
      bf16x4 pk;
#pragma unroll
      for (int reg = 0; reg < 4; reg++) pk[reg] = (bf16_t)oa[m8][reg];
      *(bf16x4*)(op + (size_t)row * ODIM + m8 * 16 + q * 4) = pk;
    }
    if (q == 0) {
      Ml[(ksplit * NROWS + row) * 2 + 0] = m_run;
      Ml[(ksplit * NROWS + row) * 2 + 1] = l_run;
    }
  }
}

// ---------------------------------------------------------------------------
// merge: combine KS partials, apply alpha/beta/h, log_softmax, write out.
// Grid 2048 x 256thr, 2 rows per wave (was 512 x 8 rows): 8 -> 32 waves/CU
// so the serial shfl-tree + partial-load latency chains overlap across waves.
// ---------------------------------------------------------------------------
__global__ __launch_bounds__(256) void merge_ls(const bf16_t* __restrict__ OpA,
                                                const bf16_t* __restrict__ OpB,
                                                const float* __restrict__ Ml,
                                                const bf16_t* __restrict__ hbf,
                                                const float* __restrict__ alpha_p,
                                                const float* __restrict__ beta_p,
                                                float* __restrict__ out) {
  int tid = threadIdx.x, lane = tid & 63, w = tid >> 6;
  float al = alpha_p[0], be = beta_p[0];
  for (int i = 0; i < 2; i++) {
    int row = blockIdx.x * 8 + w * 2 + i;
    float mk[KS], lk[KS], ak[KS];
    float M = 0.f;
#pragma unroll
    for (int ksp = 0; ksp < KS; ksp++) {
      mk[ksp] = Ml[(ksp * NROWS + row) * 2 + 0];
      lk[ksp] = Ml[(ksp * NROWS + row) * 2 + 1];
      M = fmaxf(M, mk[ksp]);
    }
    float lt = 0.f;
#pragma unroll
    for (int ksp = 0; ksp < KS; ksp++) {
      ak[ksp] = __expf(mk[ksp] - M);
      lt += lk[ksp] * ak[ksp];
    }
    float inv = al / lt;
    int d0 = lane * 2;
    float a0 = 0.f, a1 = 0.f;
#pragma unroll
    for (int ksp = 0; ksp < KS; ksp++) {
      const bf16_t* op = ksp < 6 ? OpA + (size_t)ksp * NROWS * ODIM
                                 : OpB + (size_t)(ksp - 6) * NROWS * ODIM;
      bf16x2 v = *(const bf16x2*)(op + (size_t)row * ODIM + d0);
      a0 += ak[ksp] * (float)v[0];
      a1 += ak[ksp] * (float)v[1];
    }
    bf16x2 hv = *(const bf16x2*)(hbf + (size_t)row * ODIM + d0);
    float v0 = inv * a0 + be * (float)hv[0];
    float v1 = inv * a1 + be * (float)hv[1];
    float mxv = fmaxf(v0, v1);
#pragma unroll
    for (int off = 1; off < 64; off <<= 1) mxv = fmaxf(mxv, __shfl_xor(mxv, off, 64));
    float se = __expf(v0 - mxv) + __expf(v1 - mxv);
#pragma unroll
    for (int off = 1; off < 64; off <<= 1) se += __shfl_xor(se, off, 64);
    float lz = mxv + __logf(se);
    f32x2 st = {v0 - lz, v1 - lz};
    *(f32x2*)(out + (size_t)row * ODIM + d0) = st;
  }
}

// ---------------------------------------------------------------------------
extern "C" void kernel_launch(void* const* d_in, const int* in_sizes, int n_in,
                              void* d_out, int out_size, void* d_ws,
                              size_t ws_size, hipStream_t stream) {
  const float* x     = (const float*)d_in[0];
  const float* W1    = (const float*)d_in[2];
  const float* b1    = (const float*)d_in[3];
  const float* W2    = (const float*)d_in[4];
  const float* b2    = (const float*)d_in[5];
  const float* alpha = (const float*)d_in[6];
  const float* beta  = (const float*)d_in[7];

  char* ws = (char*)d_ws;
  // [0, 25493504): xb(16M) + W1T(256K) + W2T(64K) + h1(8M) — all dead during
  // flash/merge, reused as Op splits 0..5 (24MB).
  bf16_t* xb  = (bf16_t*)(ws + 0);
  bf16_t* W1T = (bf16_t*)(ws + 16777216);
  bf16_t* W2T = (bf16_t*)(ws + 17039360);
  bf16_t* h1  = (bf16_t*)(ws + 17104896);   // ends 25493504
  bf16_t* hbf = (bf16_t*)(ws + 25493504);   // 4MB
  bf16_t* hT  = (bf16_t*)(ws + 29687808);   // 4MB
  float*  Ml  = (float*)(ws + 33882112);    // 1MB
  bf16_t* OpB = (bf16_t*)(ws + 34930688);   // 2 x 4MB -> total 43.3MB
  bf16_t* OpA = (bf16_t*)(ws + 0);          // overlays xb/W1T/W2T/h1
  float* outp = (float*)d_out;

  prep<<<1024, 256, 0, stream>>>(x, W1, W2, xb, W1T, W2T);
  gemm1<<<dim3(128, 4), 256, 0, stream>>>(xb, W1T, b1, h1);
  gemm2<<<dim3(128, 2), 256, 0, stream>>>(h1, W2T, b2, hbf, hT);
  flash<<<128 * KS, 512, 0, stream>>>(hbf, hT, OpA, OpB, Ml);
  merge_ls<<<2048, 256, 0, stream>>>(OpA, OpB, Ml, hbf, alpha, beta, outp);
}